// Round 4
// baseline (202.992 us; speedup 1.0000x reference)
//
#include <hip/hip_runtime.h>
#include <math.h>

#define VOCAB 32000
#define DD 4096
#define HH 1024
#define BB 256
#define SS 256

typedef unsigned long long u64;

// ------------------------------------------------------------- reductions ---
__device__ __forceinline__ float blockReduce256(float v, float* lds4) {
    #pragma unroll
    for (int o = 32; o; o >>= 1) v += __shfl_down(v, o);
    int lane = threadIdx.x & 63, w = threadIdx.x >> 6;
    __syncthreads();
    if (lane == 0) lds4[w] = v;
    __syncthreads();
    float tot = 0.f;
    #pragma unroll
    for (int i = 0; i < 4; ++i) tot += lds4[i];
    return tot;
}

// ------------------------------------------------------------------ pool ----
// grid (4, 257); row b==256 is the query. Block handles a 1024-col slice.
// 1028 blocks x 256 thr -> ~4+ resident/CU: smooths tail + total-variance.
__global__ void pool_kernel(const int* __restrict__ ids, const int* __restrict__ mask,
                            const int* __restrict__ qids, const int* __restrict__ qmask,
                            const float* __restrict__ embed, float* __restrict__ out) {
    __shared__ int s_off[SS];     // precomputed element offsets id*DD
    __shared__ int wofs[4];
    int b = blockIdx.y, slice = blockIdx.x, t = threadIdx.x;
    const int* I = (b < BB) ? ids  + b * SS : qids;
    const int* M = (b < BB) ? mask + b * SS : qmask;
    int id = I[t];
    int m  = M[t];
    u64 bal = __ballot(m != 0);
    int lane = t & 63, w = t >> 6;
    if (lane == 0) wofs[w] = __popcll(bal);
    __syncthreads();
    int off = 0;
    #pragma unroll
    for (int i = 0; i < 4; ++i) if (i < w) off += wofs[i];
    int total = wofs[0] + wofs[1] + wofs[2] + wofs[3];
    int pos = off + __popcll(bal & ((1ull << lane) - 1ull));
    if (m) s_off[pos] = id * DD;      // stable compaction of active rows
    __syncthreads();

    float inv = 1.0f / ((float)total + 1e-9f);
    int col = (slice << 10) + (t << 2);
    const float* eb = embed + col;
    float ax = 0.f, ay = 0.f, az = 0.f, aw = 0.f;
    int j = 0;
    for (; j + 8 <= total; j += 8) {  // 8 independent 16B loads in flight
        const float4 r0 = *(const float4*)(eb + s_off[j + 0]);
        const float4 r1 = *(const float4*)(eb + s_off[j + 1]);
        const float4 r2 = *(const float4*)(eb + s_off[j + 2]);
        const float4 r3 = *(const float4*)(eb + s_off[j + 3]);
        const float4 r4 = *(const float4*)(eb + s_off[j + 4]);
        const float4 r5 = *(const float4*)(eb + s_off[j + 5]);
        const float4 r6 = *(const float4*)(eb + s_off[j + 6]);
        const float4 r7 = *(const float4*)(eb + s_off[j + 7]);
        ax += ((r0.x + r1.x) + (r2.x + r3.x)) + ((r4.x + r5.x) + (r6.x + r7.x));
        ay += ((r0.y + r1.y) + (r2.y + r3.y)) + ((r4.y + r5.y) + (r6.y + r7.y));
        az += ((r0.z + r1.z) + (r2.z + r3.z)) + ((r4.z + r5.z) + (r6.z + r7.z));
        aw += ((r0.w + r1.w) + (r2.w + r3.w)) + ((r4.w + r5.w) + (r6.w + r7.w));
    }
    for (; j < total; ++j) {
        const float4 r0 = *(const float4*)(eb + s_off[j]);
        ax += r0.x; ay += r0.y; az += r0.z; aw += r0.w;
    }
    float4 res = make_float4(ax * inv, ay * inv, az * inv, aw * inv);
    *(float4*)(out + (size_t)b * DD + col) = res;
}

// ------------------------------------------------------------------- LN -----
__global__ void ln_kernel(float* __restrict__ x, const float* __restrict__ g,
                          const float* __restrict__ bb) {
    __shared__ float lds4[4];
    int b = blockIdx.x, t = threadIdx.x;
    float* row = x + (size_t)b * DD;
    float4 v[4];
    float s = 0.f;
    #pragma unroll
    for (int i = 0; i < 4; ++i) {
        v[i] = *(const float4*)(row + (t << 2) + (i << 10));
        s += (v[i].x + v[i].y) + (v[i].z + v[i].w);
    }
    float mu = blockReduce256(s, lds4) * (1.0f / DD);
    float q = 0.f;
    #pragma unroll
    for (int i = 0; i < 4; ++i) {
        float dx = v[i].x - mu, dy = v[i].y - mu, dz = v[i].z - mu, dw = v[i].w - mu;
        q += (dx * dx + dy * dy) + (dz * dz + dw * dw);
    }
    float var = blockReduce256(q, lds4) * (1.0f / DD);
    float sc = 1.0f / sqrtf(var + 1e-5f);
    #pragma unroll
    for (int i = 0; i < 4; ++i) {
        int col = (t << 2) + (i << 10);
        float4 gg = *(const float4*)(g + col);
        float4 bv = *(const float4*)(bb + col);
        float4 o;
        o.x = (v[i].x - mu) * sc * gg.x + bv.x;
        o.y = (v[i].y - mu) * sc * gg.y + bv.y;
        o.z = (v[i].z - mu) * sc * gg.z + bv.z;
        o.w = (v[i].w - mu) * sc * gg.w + bv.w;
        *(float4*)(row + col) = o;
    }
}

// -------------------------------------------------------------- gemm body ---
// BM=64 x BN=128, BK=32, 128 threads, 8x8 out/thread (1 B LDS per MAC).
// sX stride 68: conflict-free b128 reads (broadcast x 4 addrs).
// sW column swizzle col' = n + ((n>>5)<<2): stride-8-float reads drop to
// 2-way (free) bank aliasing.
// NPART==1: A(m,k) = A[m*ldA+k]
// NPART==8: A(m,k) = relu(sum_p A[m*ldA+k+p*partStride] + prebias[k])
template <int NPART>
__device__ __forceinline__ void gemm8x8(
        const float* __restrict__ A, const float* __restrict__ prebias,
        const float* __restrict__ Wt, float* __restrict__ Pout,
        int N, int K, int ldA, size_t partStride,
        int m0, int n0, int kBase, int Kc) {
    constexpr int BK = 32;
    __shared__ float sX[BK][68];
    __shared__ float sW[BK][140];
    int tid = threadIdx.x;
    int tx = tid & 15, ty = tid >> 4;      // out: n-octet 8*tx, m-octet 8*ty
    int r  = tid >> 3;                     // 0..15 (stage row)
    int k4 = (tid & 7) << 2;               // 0,4,...,28 (stage k)
    float acc[8][8] = {};

    for (int k0 = 0; k0 < Kc; k0 += BK) {
        int gk = kBase + k0;
        // ---- stage A: 4 passes x 16 rows, transposed scatter ----
        #pragma unroll
        for (int p = 0; p < 4; ++p) {
            int row = r + (p << 4);
            size_t ao = (size_t)(m0 + row) * ldA + gk + k4;
            float4 a = *(const float4*)(A + ao);
            if (NPART == 8) {
                #pragma unroll
                for (int pp = 1; pp < 8; ++pp) {
                    float4 e = *(const float4*)(A + ao + pp * partStride);
                    a.x += e.x; a.y += e.y; a.z += e.z; a.w += e.w;
                }
                float4 pb = *(const float4*)(prebias + gk + k4);
                a.x = fmaxf(a.x + pb.x, 0.f); a.y = fmaxf(a.y + pb.y, 0.f);
                a.z = fmaxf(a.z + pb.z, 0.f); a.w = fmaxf(a.w + pb.w, 0.f);
            }
            sX[k4 + 0][row] = a.x; sX[k4 + 1][row] = a.y;
            sX[k4 + 2][row] = a.z; sX[k4 + 3][row] = a.w;
        }
        // ---- stage W: 8 passes x 16 rows, swizzled transposed scatter ----
        #pragma unroll
        for (int p = 0; p < 8; ++p) {
            int row = r + (p << 4);
            int cs = row + ((row >> 5) << 2);
            float4 wv = *(const float4*)(Wt + (size_t)(n0 + row) * K + gk + k4);
            sW[k4 + 0][cs] = wv.x; sW[k4 + 1][cs] = wv.y;
            sW[k4 + 2][cs] = wv.z; sW[k4 + 3][cs] = wv.w;
        }
        __syncthreads();
        int wb = (tx << 3) + ((tx >> 2) << 2);   // swizzled read base
        #pragma unroll
        for (int kk = 0; kk < BK; ++kk) {
            float4 xa = *(const float4*)&sX[kk][ty << 3];
            float4 xb = *(const float4*)&sX[kk][(ty << 3) + 4];
            float4 wa = *(const float4*)&sW[kk][wb];
            float4 wc = *(const float4*)&sW[kk][wb + 4];
            float xr[8] = {xa.x, xa.y, xa.z, xa.w, xb.x, xb.y, xb.z, xb.w};
            float wr[8] = {wa.x, wa.y, wa.z, wa.w, wc.x, wc.y, wc.z, wc.w};
            #pragma unroll
            for (int i = 0; i < 8; ++i)
                #pragma unroll
                for (int j = 0; j < 8; ++j)
                    acc[i][j] += xr[i] * wr[j];
        }
        __syncthreads();
    }
    #pragma unroll
    for (int i = 0; i < 8; ++i) {
        size_t o = (size_t)(m0 + (ty << 3) + i) * N + n0 + (tx << 3);
        *(float4*)(Pout + o)     = make_float4(acc[i][0], acc[i][1], acc[i][2], acc[i][3]);
        *(float4*)(Pout + o + 4) = make_float4(acc[i][4], acc[i][5], acc[i][6], acc[i][7]);
    }
}

// -------------------------------------------------------------- gemv body ---
template <bool RELU>
__device__ __forceinline__ void gemv128(
        const float* __restrict__ x, const float* __restrict__ Wt,
        const float* __restrict__ bias, float* __restrict__ y, int K, int n) {
    __shared__ float l2[2];
    int t = threadIdx.x;
    const float* wr = Wt + (size_t)n * K;
    float s = 0.f;
    for (int k = t << 2; k < K; k += 512) {
        float4 a = *(const float4*)(x + k);
        float4 w = *(const float4*)(wr + k);
        s += (a.x * w.x + a.y * w.y) + (a.z * w.z + a.w * w.w);
    }
    #pragma unroll
    for (int o = 32; o; o >>= 1) s += __shfl_down(s, o);
    if ((t & 63) == 0) l2[t >> 6] = s;
    __syncthreads();
    if (t == 0) {
        float tot = l2[0] + l2[1] + bias[n];
        y[n] = RELU ? fmaxf(tot, 0.f) : tot;
    }
}

// --------------------------------------------------------------- layer 1 ----
// blocks [0,256): keys GEMM X @ kW1^T, split-K=8 -> P1 partials
// blocks [256,1280): query GEMV
__global__ void __launch_bounds__(128) layer1_kernel(
        const float* __restrict__ X, const float* __restrict__ kW1,
        float* __restrict__ P1,
        const float* __restrict__ qW1, const float* __restrict__ qb1,
        float* __restrict__ H1q) {
    int bid = blockIdx.x;
    if (bid < 256) {
        int bz = bid >> 5, by = (bid >> 3) & 3, bx = bid & 7;
        gemm8x8<1>(X, nullptr, kW1, P1 + (size_t)bz * BB * HH,
                   HH, DD, DD, 0, by * 64, bx * 128, bz * 512, 512);
    } else {
        gemv128<true>(X + (size_t)BB * DD, qW1, qb1, H1q, DD, bid - 256);
    }
}

// --------------------------------------------------------------- layer 2 ----
__global__ void __launch_bounds__(128) layer2_kernel(
        const float* __restrict__ P1, const float* __restrict__ kb1,
        const float* __restrict__ kW2, float* __restrict__ P2,
        const float* __restrict__ H1q, const float* __restrict__ qW2,
        const float* __restrict__ qb2, float* __restrict__ Qv) {
    int bid = blockIdx.x;
    if (bid < 256) {
        int bz = bid >> 5, by = (bid >> 3) & 3, bx = bid & 7;
        gemm8x8<8>(P1, kb1, kW2, P2 + (size_t)bz * BB * HH,
                   HH, HH, HH, (size_t)BB * HH, by * 64, bx * 128, bz * 128, 128);
    } else {
        gemv128<false>(H1q, qW2, qb2, Qv, HH, bid - 256);
    }
}

// ---------------------------------------------------------------- scores ----
// Sc[b] = sigmoid( sum_h (sum_p P2[p][b][h] + kb2[h]) * Qv[h] )
__global__ void scores_kernel(const float* __restrict__ P2, const float* __restrict__ kb2,
                              const float* __restrict__ Qv, float* __restrict__ Sc) {
    __shared__ float lds4[4];
    int b = blockIdx.x, t = threadIdx.x;
    size_t ps = (size_t)BB * HH;
    const float* pa = P2 + (size_t)b * HH;
    int h = t << 2;
    float sx = 0.f, sy = 0.f, sz = 0.f, sw = 0.f;
    #pragma unroll
    for (int p = 0; p < 8; ++p) {
        float4 e = *(const float4*)(pa + p * ps + h);
        sx += e.x; sy += e.y; sz += e.z; sw += e.w;
    }
    float4 bv = *(const float4*)(kb2 + h);
    float4 q  = *(const float4*)(Qv + h);
    float s = (sx + bv.x) * q.x + (sy + bv.y) * q.y
            + (sz + bv.z) * q.z + (sw + bv.w) * q.w;
    float tot = blockReduce256(s, lds4);
    if (t == 0) Sc[b] = 1.0f / (1.0f + expf(-tot));
}

// ------------------------------------------------------------------ topk ----
// Stable tie-break: max value, lowest index first (jax.lax.top_k semantics).
__global__ void topk_kernel(const float* __restrict__ scores, const int* __restrict__ kptr,
                            float* __restrict__ out) {
    __shared__ float ss[BB];
    __shared__ float rv[4];
    __shared__ int   ri[4];
    int t = threadIdx.x;
    ss[t] = scores[t];
    int k = kptr[0];
    if (k > BB) k = BB;
    __syncthreads();
    for (int i = 0; i < k; ++i) {
        float v = ss[t]; int vi = t;
        #pragma unroll
        for (int o = 32; o; o >>= 1) {
            float ov = __shfl_down(v, o);
            int   oi = __shfl_down(vi, o);
            if (ov > v || (ov == v && oi < vi)) { v = ov; vi = oi; }
        }
        int lane = t & 63, w = t >> 6;
        if (lane == 0) { rv[w] = v; ri[w] = vi; }
        __syncthreads();
        if (t == 0) {
            float bv = rv[0]; int bi = ri[0];
            #pragma unroll
            for (int j = 1; j < 4; ++j)
                if (rv[j] > bv || (rv[j] == bv && ri[j] < bi)) { bv = rv[j]; bi = ri[j]; }
            out[i]     = bv;
            out[k + i] = (float)bi;
            ss[bi] = -3.0e38f;
        }
        __syncthreads();
    }
}

// ---------------------------------------------------------------- launch ----
extern "C" void kernel_launch(void* const* d_in, const int* in_sizes, int n_in,
                              void* d_out, int out_size, void* d_ws, size_t ws_size,
                              hipStream_t stream) {
    const int*   input_ids  = (const int*)d_in[0];
    const int*   attn_mask  = (const int*)d_in[1];
    const int*   query_ids  = (const int*)d_in[2];
    const int*   query_mask = (const int*)d_in[3];
    const float* embed      = (const float*)d_in[4];
    const float* ln_g       = (const float*)d_in[5];
    const float* ln_b       = (const float*)d_in[6];
    const float* kW1        = (const float*)d_in[7];
    const float* kb1        = (const float*)d_in[8];
    const float* kW2        = (const float*)d_in[9];
    const float* kb2        = (const float*)d_in[10];
    const float* qW1        = (const float*)d_in[11];
    const float* qb1        = (const float*)d_in[12];
    const float* qW2        = (const float*)d_in[13];
    const float* qb2        = (const float*)d_in[14];
    const int*   kptr       = (const int*)d_in[15];

    float* ws   = (float*)d_ws;
    float* X    = ws;                            // 257*4096 (row 256 = query)
    float* P1   = X  + (size_t)(BB + 1) * DD;    // 8*256*1024
    float* H1q  = P1 + (size_t)8 * BB * HH;      // 1024
    float* P2   = H1q + HH;                      // 8*256*1024
    float* Qv   = P2 + (size_t)8 * BB * HH;      // 1024
    float* Sc   = Qv + HH;                       // 256

    pool_kernel<<<dim3(4, BB + 1), 256, 0, stream>>>(input_ids, attn_mask,
                                                     query_ids, query_mask, embed, X);
    ln_kernel<<<BB + 1, 256, 0, stream>>>(X, ln_g, ln_b);
    layer1_kernel<<<1280, 128, 0, stream>>>(X, kW1, P1, qW1, qb1, H1q);
    layer2_kernel<<<1280, 128, 0, stream>>>(P1, kb1, kW2, P2, H1q, qW2, qb2, Qv);
    scores_kernel<<<BB, 256, 0, stream>>>(P2, kb2, Qv, Sc);
    topk_kernel<<<1, 256, 0, stream>>>(Sc, kptr, (float*)d_out);
}

// Round 6
// 160.007 us; speedup vs baseline: 1.2686x; 1.2686x over previous
//
#include <hip/hip_runtime.h>
#include <math.h>

#define DD 4096
#define HH 1024
#define BB 256
#define SS 256

typedef unsigned long long u64;
typedef __attribute__((ext_vector_type(4))) short sv4;
typedef __attribute__((ext_vector_type(8))) short sv8;
typedef __attribute__((ext_vector_type(4))) float f32x4;

// ------------------------------------------------------------ bf16 split ----
__device__ __forceinline__ unsigned short f2bf(float x) {
    union { float f; unsigned u; } c; c.f = x;
    unsigned r = c.u + 0x7FFFu + ((c.u >> 16) & 1u);
    return (unsigned short)(r >> 16);
}
__device__ __forceinline__ float bf2f(unsigned short h) {
    union { unsigned u; float f; } c; c.u = ((unsigned)h) << 16;
    return c.f;
}
// x = hi + lo with hi,lo bf16 (RNE twice) -> ~2^-16 relative residual
__device__ __forceinline__ void split4(const float4& v, sv4& h, sv4& l) {
    unsigned short hx = f2bf(v.x), hy = f2bf(v.y), hz = f2bf(v.z), hw = f2bf(v.w);
    h.x = (short)hx; h.y = (short)hy; h.z = (short)hz; h.w = (short)hw;
    l.x = (short)f2bf(v.x - bf2f(hx)); l.y = (short)f2bf(v.y - bf2f(hy));
    l.z = (short)f2bf(v.z - bf2f(hz)); l.w = (short)f2bf(v.w - bf2f(hw));
}

// --------------------------------------------------- pool + LN + converts ---
// grid 1537 x 1024thr:
//   b<257   : pool row b (b==256 query) + LayerNorm; docs write split-bf16 X,
//             query writes fp32 Xq.
//   b<1281  : convert kW1 row (b-257) -> W1h/W1l
//   b<1537  : convert kW2 rows 4*(b-1281).. -> W2h/W2l
__global__ __launch_bounds__(1024) void pool_ln_cvt_kernel(
        const int* __restrict__ ids, const int* __restrict__ mask,
        const int* __restrict__ qids, const int* __restrict__ qmask,
        const float* __restrict__ embed, const float* __restrict__ ln_g,
        const float* __restrict__ ln_b,
        const float* __restrict__ kW1, const float* __restrict__ kW2,
        float* __restrict__ Xq, short* __restrict__ Xh, short* __restrict__ Xl,
        short* __restrict__ W1h, short* __restrict__ W1l,
        short* __restrict__ W2h, short* __restrict__ W2l) {
    int b = blockIdx.x, t = threadIdx.x;
    if (b >= 257) {
        if (b < 1281) {               // kW1 convert: one 4096-row per block
            int r = b - 257;
            size_t o = (size_t)r * DD + (t << 2);
            float4 v = *(const float4*)(kW1 + o);
            sv4 h, l; split4(v, h, l);
            *(sv4*)(W1h + o) = h;
            *(sv4*)(W1l + o) = l;
        } else {                      // kW2 convert: 4 rows per block
            int j = b - 1281;
            int row = (j << 2) + (t >> 8);
            int col = (t & 255) << 2;
            size_t o = (size_t)row * HH + col;
            float4 v = *(const float4*)(kW2 + o);
            sv4 h, l; split4(v, h, l);
            *(sv4*)(W2h + o) = h;
            *(sv4*)(W2l + o) = l;
        }
        return;
    }
    __shared__ int s_off[SS];
    __shared__ int wofs[4];
    __shared__ float red[16];
    const int* I = (b < BB) ? ids  + b * SS : qids;
    const int* M = (b < BB) ? mask + b * SS : qmask;
    int id = 0, m = 0;
    if (t < SS) { id = I[t]; m = M[t]; }
    u64 bal = __ballot(t < SS && m != 0);
    int lane = t & 63, w = t >> 6;
    if (t < SS && lane == 0) wofs[w] = __popcll(bal);
    __syncthreads();
    int total = wofs[0] + wofs[1] + wofs[2] + wofs[3];
    if (t < SS && m) {
        int off = 0;
        #pragma unroll
        for (int i = 0; i < 4; ++i) if (i < w) off += wofs[i];
        int pos = off + __popcll(bal & ((1ull << lane) - 1ull));
        s_off[pos] = id * DD;         // stable compaction of active rows
    }
    __syncthreads();

    float inv = 1.0f / ((float)total + 1e-9f);
    int col = t << 2;
    const float* eb = embed + col;
    float ax = 0.f, ay = 0.f, az = 0.f, aw = 0.f;
    int j = 0;
    for (; j + 8 <= total; j += 8) {  // 8 independent 16B gathers in flight
        const float4 r0 = *(const float4*)(eb + s_off[j + 0]);
        const float4 r1 = *(const float4*)(eb + s_off[j + 1]);
        const float4 r2 = *(const float4*)(eb + s_off[j + 2]);
        const float4 r3 = *(const float4*)(eb + s_off[j + 3]);
        const float4 r4 = *(const float4*)(eb + s_off[j + 4]);
        const float4 r5 = *(const float4*)(eb + s_off[j + 5]);
        const float4 r6 = *(const float4*)(eb + s_off[j + 6]);
        const float4 r7 = *(const float4*)(eb + s_off[j + 7]);
        ax += ((r0.x + r1.x) + (r2.x + r3.x)) + ((r4.x + r5.x) + (r6.x + r7.x));
        ay += ((r0.y + r1.y) + (r2.y + r3.y)) + ((r4.y + r5.y) + (r6.y + r7.y));
        az += ((r0.z + r1.z) + (r2.z + r3.z)) + ((r4.z + r5.z) + (r6.z + r7.z));
        aw += ((r0.w + r1.w) + (r2.w + r3.w)) + ((r4.w + r5.w) + (r6.w + r7.w));
    }
    for (; j < total; ++j) {
        const float4 r0 = *(const float4*)(eb + s_off[j]);
        ax += r0.x; ay += r0.y; az += r0.z; aw += r0.w;
    }
    float4 p = make_float4(ax * inv, ay * inv, az * inv, aw * inv);

    // LayerNorm (block-wide over 4096)
    float s = (p.x + p.y) + (p.z + p.w);
    #pragma unroll
    for (int o = 32; o; o >>= 1) s += __shfl_down(s, o);
    if (lane == 0) red[w] = s;
    __syncthreads();
    float mu = 0.f;
    #pragma unroll
    for (int i = 0; i < 16; ++i) mu += red[i];
    mu *= (1.0f / DD);
    float dx = p.x - mu, dy = p.y - mu, dz = p.z - mu, dw = p.w - mu;
    float q = (dx * dx + dy * dy) + (dz * dz + dw * dw);
    __syncthreads();
    #pragma unroll
    for (int o = 32; o; o >>= 1) q += __shfl_down(q, o);
    if (lane == 0) red[w] = q;
    __syncthreads();
    float var = 0.f;
    #pragma unroll
    for (int i = 0; i < 16; ++i) var += red[i];
    var *= (1.0f / DD);
    float sc = 1.0f / sqrtf(var + 1e-5f);
    float4 gg = *(const float4*)(ln_g + col);
    float4 bv = *(const float4*)(ln_b + col);
    float4 o4;
    o4.x = dx * sc * gg.x + bv.x;
    o4.y = dy * sc * gg.y + bv.y;
    o4.z = dz * sc * gg.z + bv.z;
    o4.w = dw * sc * gg.w + bv.w;
    if (b < BB) {
        sv4 h, l; split4(o4, h, l);
        *(sv4*)(Xh + (size_t)b * DD + col) = h;
        *(sv4*)(Xl + (size_t)b * DD + col) = l;
    } else {
        *(float4*)(Xq + col) = o4;
    }
}

// ------------------------------------------------- split-bf16 MFMA GEMM -----
// BM=BN=128, BK=32, 256 thr (4 waves, 2x2), wave tile 64x64 = 4x4 MFMA frags.
// 3-term: C = Ah*Bh + Ah*Bl + Al*Bh (fp32 acc). A[m][k], B[n][k] bf16 row-major.
// C/D layout (m89-verified): col = lane&15, row = (lane>>4)*4 + reg.
// STAGING (R5 bug fixed): tile = 128 rows x 32 shorts = 4096 shorts/array;
// 256 threads x 16 shorts (2x sv8 at soff, soff+8) = full coverage.
// CONTRIB: instead of storing the tile, reduce rows against Qv into
// Contrib[row][slot*2+wc] (deterministic lane-order).
template <bool CONTRIB>
__device__ void gemm_mfma(
        const short* __restrict__ Ah, const short* __restrict__ Al,
        const short* __restrict__ Bh, const short* __restrict__ Bl,
        int ldK, int m0, int n0, int kBase, int Kc, int N,
        float* __restrict__ Pout,
        const float* __restrict__ Qv, float* __restrict__ Contrib, int slot) {
    __shared__ short sAh[128 * 40] __attribute__((aligned(16)));
    __shared__ short sAl[128 * 40] __attribute__((aligned(16)));
    __shared__ short sBh[128 * 40] __attribute__((aligned(16)));
    __shared__ short sBl[128 * 40] __attribute__((aligned(16)));
    int tid = threadIdx.x;
    int lane = tid & 63, wv = tid >> 6;
    int wr = wv >> 1, wc = wv & 1;
    int l15 = lane & 15, grp = lane >> 4, lk = grp << 3;
    int srow = tid >> 1, soff = (tid & 1) << 4;   // 2 threads/row, 16 shorts each
    f32x4 zero = {0.f, 0.f, 0.f, 0.f};
    f32x4 acc[4][4];
    #pragma unroll
    for (int i = 0; i < 4; ++i)
        #pragma unroll
        for (int j = 0; j < 4; ++j) acc[i][j] = zero;

    for (int k0 = 0; k0 < Kc; k0 += 32) {
        int gk = kBase + k0;
        size_t ga = (size_t)(m0 + srow) * ldK + gk + soff;
        size_t gb = (size_t)(n0 + srow) * ldK + gk + soff;
        sv8 vah0 = *(const sv8*)(Ah + ga);
        sv8 vah1 = *(const sv8*)(Ah + ga + 8);
        sv8 val0 = *(const sv8*)(Al + ga);
        sv8 val1 = *(const sv8*)(Al + ga + 8);
        sv8 vbh0 = *(const sv8*)(Bh + gb);
        sv8 vbh1 = *(const sv8*)(Bh + gb + 8);
        sv8 vbl0 = *(const sv8*)(Bl + gb);
        sv8 vbl1 = *(const sv8*)(Bl + gb + 8);
        __syncthreads();                 // prior iter's frag reads done
        int so = srow * 40 + soff;
        *(sv8*)(sAh + so) = vah0; *(sv8*)(sAh + so + 8) = vah1;
        *(sv8*)(sAl + so) = val0; *(sv8*)(sAl + so + 8) = val1;
        *(sv8*)(sBh + so) = vbh0; *(sv8*)(sBh + so + 8) = vbh1;
        *(sv8*)(sBl + so) = vbl0; *(sv8*)(sBl + so + 8) = vbl1;
        __syncthreads();
        sv8 fah[4], fal[4], fbh[4], fbl[4];
        #pragma unroll
        for (int i = 0; i < 4; ++i) {
            int ra = (wr * 64 + i * 16 + l15) * 40 + lk;
            int rb = (wc * 64 + i * 16 + l15) * 40 + lk;
            fah[i] = *(const sv8*)(sAh + ra);
            fal[i] = *(const sv8*)(sAl + ra);
            fbh[i] = *(const sv8*)(sBh + rb);
            fbl[i] = *(const sv8*)(sBl + rb);
        }
        #pragma unroll
        for (int i = 0; i < 4; ++i)
            #pragma unroll
            for (int j = 0; j < 4; ++j) {
                acc[i][j] = __builtin_amdgcn_mfma_f32_16x16x32_bf16(fah[i], fbh[j], acc[i][j], 0, 0, 0);
                acc[i][j] = __builtin_amdgcn_mfma_f32_16x16x32_bf16(fah[i], fbl[j], acc[i][j], 0, 0, 0);
                acc[i][j] = __builtin_amdgcn_mfma_f32_16x16x32_bf16(fal[i], fbh[j], acc[i][j], 0, 0, 0);
            }
    }

    if (CONTRIB) {
        float qv[4];
        #pragma unroll
        for (int j = 0; j < 4; ++j) qv[j] = Qv[n0 + wc * 64 + j * 16 + l15];
        #pragma unroll
        for (int i = 0; i < 4; ++i)
            #pragma unroll
            for (int r = 0; r < 4; ++r) {
                float s = acc[i][0][r] * qv[0] + acc[i][1][r] * qv[1]
                        + acc[i][2][r] * qv[2] + acc[i][3][r] * qv[3];
                s += __shfl_xor(s, 1); s += __shfl_xor(s, 2);
                s += __shfl_xor(s, 4); s += __shfl_xor(s, 8);
                if (l15 == 0) {
                    int row = m0 + wr * 64 + i * 16 + grp * 4 + r;
                    Contrib[(size_t)row * 256 + slot * 2 + wc] = s;
                }
            }
    } else {
        #pragma unroll
        for (int i = 0; i < 4; ++i)
            #pragma unroll
            for (int r = 0; r < 4; ++r) {
                int row = m0 + wr * 64 + i * 16 + grp * 4 + r;
                #pragma unroll
                for (int j = 0; j < 4; ++j)
                    Pout[(size_t)row * N + n0 + wc * 64 + j * 16 + l15] = acc[i][j][r];
            }
    }
}

// --------------------------------------------------------------- layer 1 ----
// bid<256: split-K=16 MFMA GEMM X @ kW1^T -> P1[z]; bid>=256: query GEMV1.
__global__ __launch_bounds__(256) void layer1_kernel(
        const short* __restrict__ Xh, const short* __restrict__ Xl,
        const short* __restrict__ W1h, const short* __restrict__ W1l,
        float* __restrict__ P1, const float* __restrict__ Xq,
        const float* __restrict__ qW1, const float* __restrict__ qb1,
        float* __restrict__ H1q) {
    int bid = blockIdx.x;
    if (bid < 256) {
        int z = bid & 15, nb = (bid >> 4) & 7, mb = bid >> 7;
        gemm_mfma<false>(Xh, Xl, W1h, W1l, DD, mb * 128, nb * 128, z * 256, 256,
                         HH, P1 + (size_t)z * BB * HH, nullptr, nullptr, 0);
    } else {
        int i = bid - 256, wv = threadIdx.x >> 6, lane = threadIdx.x & 63;
        int n = (i << 2) + wv;
        const float* wrow = qW1 + (size_t)n * DD;
        float s = 0.f;
        #pragma unroll
        for (int jj = 0; jj < 16; ++jj) {
            int k = jj * 256 + (lane << 2);
            float4 a = *(const float4*)(Xq + k);
            float4 ww = *(const float4*)(wrow + k);
            s += (a.x * ww.x + a.y * ww.y) + (a.z * ww.z + a.w * ww.w);
        }
        #pragma unroll
        for (int o = 32; o; o >>= 1) s += __shfl_down(s, o);
        if (lane == 0) H1q[n] = fmaxf(s + qb1[n], 0.f);
    }
}

// ------------------------------------------------------ reduce1 + GEMV2 -----
// bid<256: H1[row] = relu(sum_z P1z + kb1) -> split bf16; bid>=256: Qv GEMV.
__global__ __launch_bounds__(256) void reduce1_kernel(
        const float* __restrict__ P1, const float* __restrict__ kb1,
        short* __restrict__ H1h, short* __restrict__ H1l,
        const float* __restrict__ H1q, const float* __restrict__ qW2,
        const float* __restrict__ qb2, float* __restrict__ Qv) {
    int bid = blockIdx.x, t = threadIdx.x;
    if (bid < 256) {
        int col = t << 2;
        const float* base = P1 + (size_t)bid * HH + col;
        float4 s = *(const float4*)(kb1 + col);
        #pragma unroll
        for (int z = 0; z < 16; ++z) {
            float4 p = *(const float4*)(base + (size_t)z * BB * HH);
            s.x += p.x; s.y += p.y; s.z += p.z; s.w += p.w;
        }
        s.x = fmaxf(s.x, 0.f); s.y = fmaxf(s.y, 0.f);
        s.z = fmaxf(s.z, 0.f); s.w = fmaxf(s.w, 0.f);
        sv4 h, l; split4(s, h, l);
        size_t o = (size_t)bid * HH + col;
        *(sv4*)(H1h + o) = h;
        *(sv4*)(H1l + o) = l;
    } else {
        int i = bid - 256, wv = t >> 6, lane = t & 63;
        int n = (i << 2) + wv;
        const float* wrow = qW2 + (size_t)n * HH;
        float s = 0.f;
        #pragma unroll
        for (int jj = 0; jj < 4; ++jj) {
            int k = jj * 256 + (lane << 2);
            float4 a = *(const float4*)(H1q + k);
            float4 ww = *(const float4*)(wrow + k);
            s += (a.x * ww.x + a.y * ww.y) + (a.z * ww.z + a.w * ww.w);
        }
        #pragma unroll
        for (int o = 32; o; o >>= 1) s += __shfl_down(s, o);
        if (lane == 0) Qv[n] = s + qb2[n];
    }
}

// --------------------------------------------------------------- layer 2 ----
// split-K=16 MFMA GEMM H1 @ kW2^T, tile reduced against Qv -> Contrib.
__global__ __launch_bounds__(256) void layer2_kernel(
        const short* __restrict__ H1h, const short* __restrict__ H1l,
        const short* __restrict__ W2h, const short* __restrict__ W2l,
        const float* __restrict__ Qv, float* __restrict__ Contrib) {
    int bid = blockIdx.x;
    int z = bid & 15, nb = (bid >> 4) & 7, mb = bid >> 7;
    gemm_mfma<true>(H1h, H1l, W2h, W2l, HH, mb * 128, nb * 128, z * 64, 64,
                    HH, nullptr, Qv, Contrib, z * 8 + nb);
}

// ------------------------------------------------- final: scores + topk -----
__global__ __launch_bounds__(1024) void final_kernel(
        const float* __restrict__ Contrib, const float* __restrict__ kb2,
        const float* __restrict__ Qv, const int* __restrict__ kptr,
        float* __restrict__ out) {
    __shared__ float red[16];
    __shared__ float ss[BB];
    __shared__ float rv[16];
    __shared__ int   ri[16];
    __shared__ float s_bq;
    int t = threadIdx.x, lane = t & 63, w = t >> 6;
    float v = kb2[t] * Qv[t];
    #pragma unroll
    for (int o = 32; o; o >>= 1) v += __shfl_down(v, o);
    if (lane == 0) red[w] = v;
    __syncthreads();
    if (t == 0) {
        float b = 0.f;
        #pragma unroll
        for (int i = 0; i < 16; ++i) b += red[i];
        s_bq = b;
    }
    __syncthreads();
    if (t < BB) {
        const float* c = Contrib + (size_t)t * 256;
        float sx = 0.f, sy = 0.f, sz = 0.f, sw = 0.f;
        for (int j = 0; j < 256; j += 4) {
            float4 e = *(const float4*)(c + j);
            sx += e.x; sy += e.y; sz += e.z; sw += e.w;
        }
        float lg = s_bq + ((sx + sy) + (sz + sw));
        ss[t] = 1.0f / (1.0f + expf(-lg));
    }
    __syncthreads();
    int k = kptr[0];
    if (k > BB) k = BB;
    for (int i = 0; i < k; ++i) {
        float vv = (t < BB) ? ss[t] : -3.3e38f;
        int vi = t;
        #pragma unroll
        for (int o = 32; o; o >>= 1) {
            float ov = __shfl_down(vv, o);
            int   oi = __shfl_down(vi, o);
            if (ov > vv || (ov == vv && oi < vi)) { vv = ov; vi = oi; }
        }
        if (lane == 0) { rv[w] = vv; ri[w] = vi; }
        __syncthreads();
        if (t == 0) {
            float bv = rv[0]; int bi = ri[0];
            #pragma unroll
            for (int j = 1; j < 16; ++j)
                if (rv[j] > bv || (rv[j] == bv && ri[j] < bi)) { bv = rv[j]; bi = ri[j]; }
            out[i]     = bv;
            out[k + i] = (float)bi;
            ss[bi] = -3.0e38f;
        }
        __syncthreads();
    }
}

// ---------------------------------------------------------------- launch ----
extern "C" void kernel_launch(void* const* d_in, const int* in_sizes, int n_in,
                              void* d_out, int out_size, void* d_ws, size_t ws_size,
                              hipStream_t stream) {
    const int*   input_ids  = (const int*)d_in[0];
    const int*   attn_mask  = (const int*)d_in[1];
    const int*   query_ids  = (const int*)d_in[2];
    const int*   query_mask = (const int*)d_in[3];
    const float* embed      = (const float*)d_in[4];
    const float* ln_g       = (const float*)d_in[5];
    const float* ln_b       = (const float*)d_in[6];
    const float* kW1        = (const float*)d_in[7];
    const float* kb1        = (const float*)d_in[8];
    const float* kW2        = (const float*)d_in[9];
    const float* kb2        = (const float*)d_in[10];
    const float* qW1        = (const float*)d_in[11];
    const float* qb1        = (const float*)d_in[12];
    const float* qW2        = (const float*)d_in[13];
    const float* qb2        = (const float*)d_in[14];
    const int*   kptr       = (const int*)d_in[15];

    char* p = (char*)d_ws;
    auto carve = [&](size_t bytes) {
        char* r = p;
        p += (bytes + 255) & ~(size_t)255;
        return r;
    };
    float* Xq      = (float*)carve((size_t)DD * 4);
    short* Xh      = (short*)carve((size_t)BB * DD * 2);
    short* Xl      = (short*)carve((size_t)BB * DD * 2);
    short* W1h     = (short*)carve((size_t)HH * DD * 2);
    short* W1l     = (short*)carve((size_t)HH * DD * 2);
    short* W2h     = (short*)carve((size_t)HH * HH * 2);
    short* W2l     = (short*)carve((size_t)HH * HH * 2);
    float* P1      = (float*)carve((size_t)16 * BB * HH * 4);
    float* H1q     = (float*)carve((size_t)HH * 4);
    short* H1h     = (short*)carve((size_t)BB * HH * 2);
    short* H1l     = (short*)carve((size_t)BB * HH * 2);
    float* Qv      = (float*)carve((size_t)HH * 4);
    float* Contrib = (float*)carve((size_t)BB * 256 * 4);

    pool_ln_cvt_kernel<<<1537, 1024, 0, stream>>>(
        input_ids, attn_mask, query_ids, query_mask, embed, ln_g, ln_b,
        kW1, kW2, Xq, Xh, Xl, W1h, W1l, W2h, W2l);
    layer1_kernel<<<512, 256, 0, stream>>>(Xh, Xl, W1h, W1l, P1, Xq, qW1, qb1, H1q);
    reduce1_kernel<<<512, 256, 0, stream>>>(P1, kb1, H1h, H1l, H1q, qW2, qb2, Qv);
    layer2_kernel<<<256, 256, 0, stream>>>(H1h, H1l, W2h, W2l, Qv, Contrib);
    final_kernel<<<1, 1024, 0, stream>>>(Contrib, kb2, Qv, kptr, (float*)d_out);
}

// Round 7
// 141.047 us; speedup vs baseline: 1.4392x; 1.1344x over previous
//
#include <hip/hip_runtime.h>
#include <math.h>

#define DD 4096
#define HH 1024
#define BB 256
#define SS 256

typedef unsigned long long u64;
typedef __attribute__((ext_vector_type(4))) short sv4;
typedef __attribute__((ext_vector_type(8))) short sv8;
typedef __attribute__((ext_vector_type(4))) float f32x4;

// ------------------------------------------------------------ bf16 split ----
__device__ __forceinline__ unsigned short f2bf(float x) {
    union { float f; unsigned u; } c; c.f = x;
    unsigned r = c.u + 0x7FFFu + ((c.u >> 16) & 1u);
    return (unsigned short)(r >> 16);
}
__device__ __forceinline__ float bf2f(unsigned short h) {
    union { unsigned u; float f; } c; c.u = ((unsigned)h) << 16;
    return c.f;
}
// x = hi + lo with hi,lo bf16 (RNE twice) -> ~2^-16 relative residual
__device__ __forceinline__ void split4(const float4& v, sv4& h, sv4& l) {
    unsigned short hx = f2bf(v.x), hy = f2bf(v.y), hz = f2bf(v.z), hw = f2bf(v.w);
    h.x = (short)hx; h.y = (short)hy; h.z = (short)hz; h.w = (short)hw;
    l.x = (short)f2bf(v.x - bf2f(hx)); l.y = (short)f2bf(v.y - bf2f(hy));
    l.z = (short)f2bf(v.z - bf2f(hz)); l.w = (short)f2bf(v.w - bf2f(hw));
}
// two float4 (16 consecutive floats) -> sv8 hi + sv8 lo
__device__ __forceinline__ void split8(const float4& a, const float4& b,
                                       sv8& h, sv8& l) {
    sv4 h0, l0, h1, l1;
    split4(a, h0, l0);
    split4(b, h1, l1);
    h.s0 = h0.x; h.s1 = h0.y; h.s2 = h0.z; h.s3 = h0.w;
    h.s4 = h1.x; h.s5 = h1.y; h.s6 = h1.z; h.s7 = h1.w;
    l.s0 = l0.x; l.s1 = l0.y; l.s2 = l0.z; l.s3 = l0.w;
    l.s4 = l1.x; l.s5 = l1.y; l.s6 = l1.z; l.s7 = l1.w;
}

// ------------------------------------------------------------------ prep ----
// 257 blocks x 256 thr. Compact active ids (stable), bitonic-sort ascending,
// write SortedOff[b][i] = id*DD and Count[b]. Sorted order => concurrent
// doc-blocks sweep embed in ascending address order (LLC reuse of the ~38%
// duplicate rows). Sum-reorder is numerically safe (vals saturate / thresholds).
__global__ __launch_bounds__(256) void prep_kernel(
        const int* __restrict__ ids, const int* __restrict__ mask,
        const int* __restrict__ qids, const int* __restrict__ qmask,
        int* __restrict__ SortedOff, int* __restrict__ Count) {
    __shared__ int s_key[256];
    __shared__ int wofs[4];
    int b = blockIdx.x, t = threadIdx.x;
    const int* I = (b < BB) ? ids  + b * SS : qids;
    const int* M = (b < BB) ? mask + b * SS : qmask;
    int id = I[t], m = M[t];
    u64 bal = __ballot(m != 0);
    int lane = t & 63, w = t >> 6;
    if (lane == 0) wofs[w] = __popcll(bal);
    s_key[t] = 0x7FFFFFFF;
    __syncthreads();
    int off = 0;
    #pragma unroll
    for (int i = 0; i < 4; ++i) if (i < w) off += wofs[i];
    int total = wofs[0] + wofs[1] + wofs[2] + wofs[3];
    if (m) s_key[off + __popcll(bal & ((1ull << lane) - 1ull))] = id;
    __syncthreads();
    // bitonic sort, ascending, n=256, one element per thread
    for (int k = 2; k <= 256; k <<= 1) {
        for (int j = k >> 1; j > 0; j >>= 1) {
            int p = t ^ j;
            int a = s_key[t], c = s_key[p];
            bool dir = ((t & k) == 0);
            bool keepMin = ((t < p) == dir);
            int nv = keepMin ? (a < c ? a : c) : (a > c ? a : c);
            __syncthreads();
            s_key[t] = nv;
            __syncthreads();
        }
    }
    SortedOff[b * 256 + t] = (t < total) ? s_key[t] * DD : 0;
    if (t == 0) Count[b] = total;
}

// ------------------------------------------------------------------ pool ----
// grid 4112 = 257 docs x 16 slices (doc = bid>>4), 64 thr. Slice = 256 cols.
// 8 gather rows in flight (8 KB/wave); ~16 blocks/CU -> tail ~6%.
__global__ __launch_bounds__(64) void pool_kernel(
        const int* __restrict__ SortedOff, const int* __restrict__ Count,
        const float* __restrict__ embed, float* __restrict__ Pooled) {
    __shared__ int s_off[256];
    int bid = blockIdx.x, t = threadIdx.x;
    int doc = bid >> 4, slice = bid & 15;
    int total = Count[doc];
    #pragma unroll
    for (int i = 0; i < 4; ++i) s_off[t + i * 64] = SortedOff[doc * 256 + t + i * 64];
    __syncthreads();
    float inv = 1.0f / ((float)total + 1e-9f);
    int col = (slice << 8) + (t << 2);
    const float* eb = embed + col;
    float ax = 0.f, ay = 0.f, az = 0.f, aw = 0.f;
    int j = 0;
    for (; j + 8 <= total; j += 8) {
        const float4 r0 = *(const float4*)(eb + s_off[j + 0]);
        const float4 r1 = *(const float4*)(eb + s_off[j + 1]);
        const float4 r2 = *(const float4*)(eb + s_off[j + 2]);
        const float4 r3 = *(const float4*)(eb + s_off[j + 3]);
        const float4 r4 = *(const float4*)(eb + s_off[j + 4]);
        const float4 r5 = *(const float4*)(eb + s_off[j + 5]);
        const float4 r6 = *(const float4*)(eb + s_off[j + 6]);
        const float4 r7 = *(const float4*)(eb + s_off[j + 7]);
        ax += ((r0.x + r1.x) + (r2.x + r3.x)) + ((r4.x + r5.x) + (r6.x + r7.x));
        ay += ((r0.y + r1.y) + (r2.y + r3.y)) + ((r4.y + r5.y) + (r6.y + r7.y));
        az += ((r0.z + r1.z) + (r2.z + r3.z)) + ((r4.z + r5.z) + (r6.z + r7.z));
        aw += ((r0.w + r1.w) + (r2.w + r3.w)) + ((r4.w + r5.w) + (r6.w + r7.w));
    }
    for (; j < total; ++j) {
        const float4 r0 = *(const float4*)(eb + s_off[j]);
        ax += r0.x; ay += r0.y; az += r0.z; aw += r0.w;
    }
    *(float4*)(Pooled + (size_t)doc * DD + col) =
        make_float4(ax * inv, ay * inv, az * inv, aw * inv);
}

// -------------------------------------------------------------- LN+split ----
// 257 blocks x 256 thr: LayerNorm Pooled row; docs -> split bf16 Xh/Xl,
// query (b==256) -> fp32 Xq.
__global__ __launch_bounds__(256) void ln_split_kernel(
        const float* __restrict__ Pooled, const float* __restrict__ g,
        const float* __restrict__ bb, short* __restrict__ Xh,
        short* __restrict__ Xl, float* __restrict__ Xq) {
    __shared__ float lds4[4];
    int b = blockIdx.x, t = threadIdx.x;
    const float* row = Pooled + (size_t)b * DD;
    float4 v[4];
    float s = 0.f;
    #pragma unroll
    for (int i = 0; i < 4; ++i) {
        v[i] = *(const float4*)(row + (t << 2) + (i << 10));
        s += (v[i].x + v[i].y) + (v[i].z + v[i].w);
    }
    // block reduce (256 thr)
    #pragma unroll
    for (int o = 32; o; o >>= 1) s += __shfl_down(s, o);
    int lane = t & 63, w = t >> 6;
    if (lane == 0) lds4[w] = s;
    __syncthreads();
    float mu = (lds4[0] + lds4[1] + lds4[2] + lds4[3]) * (1.0f / DD);
    float q = 0.f;
    #pragma unroll
    for (int i = 0; i < 4; ++i) {
        float dx = v[i].x - mu, dy = v[i].y - mu, dz = v[i].z - mu, dw = v[i].w - mu;
        q += (dx * dx + dy * dy) + (dz * dz + dw * dw);
    }
    __syncthreads();
    #pragma unroll
    for (int o = 32; o; o >>= 1) q += __shfl_down(q, o);
    if (lane == 0) lds4[w] = q;
    __syncthreads();
    float var = (lds4[0] + lds4[1] + lds4[2] + lds4[3]) * (1.0f / DD);
    float sc = 1.0f / sqrtf(var + 1e-5f);
    #pragma unroll
    for (int i = 0; i < 4; ++i) {
        int col = (t << 2) + (i << 10);
        float4 gg = *(const float4*)(g + col);
        float4 bv = *(const float4*)(bb + col);
        float4 o4;
        o4.x = (v[i].x - mu) * sc * gg.x + bv.x;
        o4.y = (v[i].y - mu) * sc * gg.y + bv.y;
        o4.z = (v[i].z - mu) * sc * gg.z + bv.z;
        o4.w = (v[i].w - mu) * sc * gg.w + bv.w;
        if (b < BB) {
            sv4 h, l; split4(o4, h, l);
            *(sv4*)(Xh + (size_t)b * DD + col) = h;
            *(sv4*)(Xl + (size_t)b * DD + col) = l;
        } else {
            *(float4*)(Xq + col) = o4;
        }
    }
}

// ------------------------------------------------- split-bf16 MFMA GEMM -----
// BM=BN=128, BK=32, 256 thr (4 waves 2x2), wave tile 64x64 = 4x4 16x16 frags.
// 3-term: C = Ah*Bh + Ah*Bl + Al*Bh (fp32 acc). A split-bf16; B fp32 weights
// split in-staging (bit-identical to pre-converted). C/D layout (m89):
// col = lane&15, row = (lane>>4)*4 + reg.
template <bool CONTRIB>
__device__ void gemm_mfma(
        const short* __restrict__ Ah, const short* __restrict__ Al,
        const float* __restrict__ Wf,
        int ldK, int m0, int n0, int kBase, int Kc, int N,
        float* __restrict__ Pout,
        const float* __restrict__ Qv, float* __restrict__ Contrib, int slot) {
    __shared__ short sAh[128 * 40] __attribute__((aligned(16)));
    __shared__ short sAl[128 * 40] __attribute__((aligned(16)));
    __shared__ short sBh[128 * 40] __attribute__((aligned(16)));
    __shared__ short sBl[128 * 40] __attribute__((aligned(16)));
    int tid = threadIdx.x;
    int lane = tid & 63, wv = tid >> 6;
    int wr = wv >> 1, wc = wv & 1;
    int l15 = lane & 15, grp = lane >> 4, lk = grp << 3;
    int srow = tid >> 1, soff = (tid & 1) << 4;   // 2 thr/row, 16 elems each
    f32x4 zero = {0.f, 0.f, 0.f, 0.f};
    f32x4 acc[4][4];
    #pragma unroll
    for (int i = 0; i < 4; ++i)
        #pragma unroll
        for (int j = 0; j < 4; ++j) acc[i][j] = zero;

    for (int k0 = 0; k0 < Kc; k0 += 32) {
        int gk = kBase + k0;
        size_t ga = (size_t)(m0 + srow) * ldK + gk + soff;
        sv8 vah0 = *(const sv8*)(Ah + ga);
        sv8 vah1 = *(const sv8*)(Ah + ga + 8);
        sv8 val0 = *(const sv8*)(Al + ga);
        sv8 val1 = *(const sv8*)(Al + ga + 8);
        const float* wp = Wf + (size_t)(n0 + srow) * ldK + gk + soff;
        float4 w0 = *(const float4*)(wp);
        float4 w1 = *(const float4*)(wp + 4);
        float4 w2 = *(const float4*)(wp + 8);
        float4 w3 = *(const float4*)(wp + 12);
        sv8 bh0, bl0, bh1, bl1;
        split8(w0, w1, bh0, bl0);
        split8(w2, w3, bh1, bl1);
        __syncthreads();                 // prior iter's frag reads done
        int so = srow * 40 + soff;
        *(sv8*)(sAh + so) = vah0; *(sv8*)(sAh + so + 8) = vah1;
        *(sv8*)(sAl + so) = val0; *(sv8*)(sAl + so + 8) = val1;
        *(sv8*)(sBh + so) = bh0;  *(sv8*)(sBh + so + 8) = bh1;
        *(sv8*)(sBl + so) = bl0;  *(sv8*)(sBl + so + 8) = bl1;
        __syncthreads();
        sv8 fah[4], fal[4], fbh[4], fbl[4];
        #pragma unroll
        for (int i = 0; i < 4; ++i) {
            int ra = (wr * 64 + i * 16 + l15) * 40 + lk;
            int rb = (wc * 64 + i * 16 + l15) * 40 + lk;
            fah[i] = *(const sv8*)(sAh + ra);
            fal[i] = *(const sv8*)(sAl + ra);
            fbh[i] = *(const sv8*)(sBh + rb);
            fbl[i] = *(const sv8*)(sBl + rb);
        }
        #pragma unroll
        for (int i = 0; i < 4; ++i)
            #pragma unroll
            for (int j = 0; j < 4; ++j) {
                acc[i][j] = __builtin_amdgcn_mfma_f32_16x16x32_bf16(fah[i], fbh[j], acc[i][j], 0, 0, 0);
                acc[i][j] = __builtin_amdgcn_mfma_f32_16x16x32_bf16(fah[i], fbl[j], acc[i][j], 0, 0, 0);
                acc[i][j] = __builtin_amdgcn_mfma_f32_16x16x32_bf16(fal[i], fbh[j], acc[i][j], 0, 0, 0);
            }
    }

    if (CONTRIB) {
        float qv[4];
        #pragma unroll
        for (int j = 0; j < 4; ++j) qv[j] = Qv[n0 + wc * 64 + j * 16 + l15];
        #pragma unroll
        for (int i = 0; i < 4; ++i)
            #pragma unroll
            for (int r = 0; r < 4; ++r) {
                float s = acc[i][0][r] * qv[0] + acc[i][1][r] * qv[1]
                        + acc[i][2][r] * qv[2] + acc[i][3][r] * qv[3];
                s += __shfl_xor(s, 1); s += __shfl_xor(s, 2);
                s += __shfl_xor(s, 4); s += __shfl_xor(s, 8);
                if (l15 == 0) {
                    int row = m0 + wr * 64 + i * 16 + grp * 4 + r;
                    Contrib[(size_t)row * 256 + slot * 2 + wc] = s;
                }
            }
    } else {
        #pragma unroll
        for (int i = 0; i < 4; ++i)
            #pragma unroll
            for (int r = 0; r < 4; ++r) {
                int row = m0 + wr * 64 + i * 16 + grp * 4 + r;
                #pragma unroll
                for (int j = 0; j < 4; ++j)
                    Pout[(size_t)row * N + n0 + wc * 64 + j * 16 + l15] = acc[i][j][r];
            }
    }
}

// --------------------------------------------------------------- layer 1 ----
// bid<256: split-K=16 MFMA GEMM X @ kW1^T -> P1[z]; bid>=256: query GEMV1.
__global__ __launch_bounds__(256) void layer1_kernel(
        const short* __restrict__ Xh, const short* __restrict__ Xl,
        const float* __restrict__ kW1,
        float* __restrict__ P1, const float* __restrict__ Xq,
        const float* __restrict__ qW1, const float* __restrict__ qb1,
        float* __restrict__ H1q) {
    int bid = blockIdx.x;
    if (bid < 256) {
        int z = bid & 15, nb = (bid >> 4) & 7, mb = bid >> 7;
        gemm_mfma<false>(Xh, Xl, kW1, DD, mb * 128, nb * 128, z * 256, 256,
                         HH, P1 + (size_t)z * BB * HH, nullptr, nullptr, 0);
    } else {
        int i = bid - 256, wv = threadIdx.x >> 6, lane = threadIdx.x & 63;
        int n = (i << 2) + wv;
        const float* wrow = qW1 + (size_t)n * DD;
        float s = 0.f;
        #pragma unroll
        for (int jj = 0; jj < 16; ++jj) {
            int k = jj * 256 + (lane << 2);
            float4 a = *(const float4*)(Xq + k);
            float4 ww = *(const float4*)(wrow + k);
            s += (a.x * ww.x + a.y * ww.y) + (a.z * ww.z + a.w * ww.w);
        }
        #pragma unroll
        for (int o = 32; o; o >>= 1) s += __shfl_down(s, o);
        if (lane == 0) H1q[n] = fmaxf(s + qb1[n], 0.f);
    }
}

// ------------------------------------------------------ reduce1 + GEMV2 -----
// bid<256: H1[row] = relu(sum_z P1z + kb1) -> split bf16; bid>=256: Qv GEMV.
__global__ __launch_bounds__(256) void reduce1_kernel(
        const float* __restrict__ P1, const float* __restrict__ kb1,
        short* __restrict__ H1h, short* __restrict__ H1l,
        const float* __restrict__ H1q, const float* __restrict__ qW2,
        const float* __restrict__ qb2, float* __restrict__ Qv) {
    int bid = blockIdx.x, t = threadIdx.x;
    if (bid < 256) {
        int col = t << 2;
        const float* base = P1 + (size_t)bid * HH + col;
        float4 s = *(const float4*)(kb1 + col);
        #pragma unroll
        for (int z = 0; z < 16; ++z) {
            float4 p = *(const float4*)(base + (size_t)z * BB * HH);
            s.x += p.x; s.y += p.y; s.z += p.z; s.w += p.w;
        }
        s.x = fmaxf(s.x, 0.f); s.y = fmaxf(s.y, 0.f);
        s.z = fmaxf(s.z, 0.f); s.w = fmaxf(s.w, 0.f);
        sv4 h, l; split4(s, h, l);
        size_t o = (size_t)bid * HH + col;
        *(sv4*)(H1h + o) = h;
        *(sv4*)(H1l + o) = l;
    } else {
        int i = bid - 256, wv = t >> 6, lane = t & 63;
        int n = (i << 2) + wv;
        const float* wrow = qW2 + (size_t)n * HH;
        float s = 0.f;
        #pragma unroll
        for (int jj = 0; jj < 4; ++jj) {
            int k = jj * 256 + (lane << 2);
            float4 a = *(const float4*)(H1q + k);
            float4 ww = *(const float4*)(wrow + k);
            s += (a.x * ww.x + a.y * ww.y) + (a.z * ww.z + a.w * ww.w);
        }
        #pragma unroll
        for (int o = 32; o; o >>= 1) s += __shfl_down(s, o);
        if (lane == 0) Qv[n] = s + qb2[n];
    }
}

// --------------------------------------------------------------- layer 2 ----
// split-K=16 MFMA GEMM H1 @ kW2^T, tile reduced against Qv -> Contrib.
__global__ __launch_bounds__(256) void layer2_kernel(
        const short* __restrict__ H1h, const short* __restrict__ H1l,
        const float* __restrict__ kW2,
        const float* __restrict__ Qv, float* __restrict__ Contrib) {
    int bid = blockIdx.x;
    int z = bid & 15, nb = (bid >> 4) & 7, mb = bid >> 7;
    gemm_mfma<true>(H1h, H1l, kW2, HH, mb * 128, nb * 128, z * 64, 64,
                    HH, nullptr, Qv, Contrib, z * 8 + nb);
}

// ------------------------------------------------- final: scores + topk -----
__global__ __launch_bounds__(1024) void final_kernel(
        const float* __restrict__ Contrib, const float* __restrict__ kb2,
        const float* __restrict__ Qv, const int* __restrict__ kptr,
        float* __restrict__ out) {
    __shared__ float red[16];
    __shared__ float ss[BB];
    __shared__ float rv[16];
    __shared__ int   ri[16];
    __shared__ float s_bq;
    int t = threadIdx.x, lane = t & 63, w = t >> 6;
    float v = kb2[t] * Qv[t];
    #pragma unroll
    for (int o = 32; o; o >>= 1) v += __shfl_down(v, o);
    if (lane == 0) red[w] = v;
    __syncthreads();
    if (t == 0) {
        float b = 0.f;
        #pragma unroll
        for (int i = 0; i < 16; ++i) b += red[i];
        s_bq = b;
    }
    __syncthreads();
    if (t < BB) {
        const float* c = Contrib + (size_t)t * 256;
        float sx = 0.f, sy = 0.f, sz = 0.f, sw = 0.f;
        for (int j = 0; j < 256; j += 4) {
            float4 e = *(const float4*)(c + j);
            sx += e.x; sy += e.y; sz += e.z; sw += e.w;
        }
        float lg = s_bq + ((sx + sy) + (sz + sw));
        ss[t] = 1.0f / (1.0f + expf(-lg));
    }
    __syncthreads();
    int k = kptr[0];
    if (k > BB) k = BB;
    for (int i = 0; i < k; ++i) {
        float vv = (t < BB) ? ss[t] : -3.3e38f;
        int vi = t;
        #pragma unroll
        for (int o = 32; o; o >>= 1) {
            float ov = __shfl_down(vv, o);
            int   oi = __shfl_down(vi, o);
            if (ov > vv || (ov == vv && oi < vi)) { vv = ov; vi = oi; }
        }
        if (lane == 0) { rv[w] = vv; ri[w] = vi; }
        __syncthreads();
        if (t == 0) {
            float bv = rv[0]; int bi = ri[0];
            #pragma unroll
            for (int j = 1; j < 16; ++j)
                if (rv[j] > bv || (rv[j] == bv && ri[j] < bi)) { bv = rv[j]; bi = ri[j]; }
            out[i]     = bv;
            out[k + i] = (float)bi;
            ss[bi] = -3.0e38f;
        }
        __syncthreads();
    }
}

// ---------------------------------------------------------------- launch ----
extern "C" void kernel_launch(void* const* d_in, const int* in_sizes, int n_in,
                              void* d_out, int out_size, void* d_ws, size_t ws_size,
                              hipStream_t stream) {
    const int*   input_ids  = (const int*)d_in[0];
    const int*   attn_mask  = (const int*)d_in[1];
    const int*   query_ids  = (const int*)d_in[2];
    const int*   query_mask = (const int*)d_in[3];
    const float* embed      = (const float*)d_in[4];
    const float* ln_g       = (const float*)d_in[5];
    const float* ln_b       = (const float*)d_in[6];
    const float* kW1        = (const float*)d_in[7];
    const float* kb1        = (const float*)d_in[8];
    const float* kW2        = (const float*)d_in[9];
    const float* kb2        = (const float*)d_in[10];
    const float* qW1        = (const float*)d_in[11];
    const float* qb1        = (const float*)d_in[12];
    const float* qW2        = (const float*)d_in[13];
    const float* qb2        = (const float*)d_in[14];
    const int*   kptr       = (const int*)d_in[15];

    char* p = (char*)d_ws;
    auto carve = [&](size_t bytes) {
        char* r = p;
        p += (bytes + 255) & ~(size_t)255;
        return r;
    };
    int*   SortedOff = (int*)carve((size_t)257 * 256 * 4);
    int*   Count     = (int*)carve((size_t)257 * 4);
    float* Pooled    = (float*)carve((size_t)257 * DD * 4);
    float* Xq        = (float*)carve((size_t)DD * 4);
    short* Xh        = (short*)carve((size_t)BB * DD * 2);
    short* Xl        = (short*)carve((size_t)BB * DD * 2);
    float* P1        = (float*)carve((size_t)16 * BB * HH * 4);
    float* H1q       = (float*)carve((size_t)HH * 4);
    short* H1h       = (short*)carve((size_t)BB * HH * 2);
    short* H1l       = (short*)carve((size_t)BB * HH * 2);
    float* Qv        = (float*)carve((size_t)HH * 4);
    float* Contrib   = (float*)carve((size_t)BB * 256 * 4);

    prep_kernel<<<257, 256, 0, stream>>>(input_ids, attn_mask, query_ids,
                                         query_mask, SortedOff, Count);
    pool_kernel<<<4112, 64, 0, stream>>>(SortedOff, Count, embed, Pooled);
    ln_split_kernel<<<257, 256, 0, stream>>>(Pooled, ln_g, ln_b, Xh, Xl, Xq);
    layer1_kernel<<<512, 256, 0, stream>>>(Xh, Xl, kW1, P1, Xq, qW1, qb1, H1q);
    reduce1_kernel<<<512, 256, 0, stream>>>(P1, kb1, H1h, H1l, H1q, qW2, qb2, Qv);
    layer2_kernel<<<256, 256, 0, stream>>>(H1h, H1l, kW2, Qv, Contrib);
    final_kernel<<<1, 1024, 0, stream>>>(Contrib, kb2, Qv, kptr, (float*)d_out);
}